// Round 2
// baseline (2501.767 us; speedup 1.0000x reference)
//
#include <hip/hip_runtime.h>
#include <hip/hip_bf16.h>
#include <stdint.h>

#define DI __device__ __forceinline__

typedef __attribute__((ext_vector_type(4))) float f32x4;
typedef __attribute__((ext_vector_type(8))) short bf16x8;   // 8 bf16 = 4 VGPR (MFMA A/B frag)
typedef __attribute__((ext_vector_type(4))) short s16x4;

typedef unsigned short ushort_t;

constexpr int M_ = 16384;   // B*T
constexpr int N_ = 4096;    // OUT
constexpr int K_ = 4096;    // IN
constexpr int R_ = 64;

// ---------- bf16 split helpers ----------
DI ushort_t f32_to_bf16_rne(float f) {
    unsigned u = __builtin_bit_cast(unsigned, f);
    u += 0x7FFFu + ((u >> 16) & 1u);           // round-nearest-even
    return (ushort_t)(u >> 16);
}
DI float bf16_to_f32(ushort_t h) {
    return __builtin_bit_cast(float, (unsigned)h << 16);
}

DI void async_cp16(const void* g, void* l) {
    __builtin_amdgcn_global_load_lds(
        (const __attribute__((address_space(1))) unsigned*)g,
        (__attribute__((address_space(3))) unsigned*)l, 16, 0, 0);
}

// ---------- prep 1: US[n][r] = U[n][r] * S[r] ----------
__global__ __launch_bounds__(256) void k_fold_us(const float* __restrict__ U,
                                                 const float* __restrict__ S,
                                                 float* __restrict__ US) {
    int i = blockIdx.x * 256 + threadIdx.x;
    if (i < N_ * R_) US[i] = U[i] * S[i & (R_ - 1)];
}

// ---------- prep 2: W = weight_main + US @ V  ->  planar hiW, loW (bf16) ----------
// block computes 64 n-rows x 128 k-cols
__global__ __launch_bounds__(256) void k_fuse_w(const float* __restrict__ WM,
                                                const float* __restrict__ US,
                                                const float* __restrict__ V,
                                                ushort_t* __restrict__ hiW,
                                                ushort_t* __restrict__ loW) {
    __shared__ __align__(16) float sUS[64][68];    // padded rows
    __shared__ __align__(16) float sV[64][128];
    int t = threadIdx.x;
    int n0 = (blockIdx.x >> 5) * 64;
    int k0 = (blockIdx.x & 31) * 128;
#pragma unroll
    for (int j = 0; j < 4; ++j) {                  // US tile 64x64
        int f = j * 1024 + t * 4;
        int r = f >> 6, c = f & 63;
        *(f32x4*)&sUS[r][c] = *(const f32x4*)&US[(size_t)(n0 + r) * R_ + c];
    }
#pragma unroll
    for (int j = 0; j < 8; ++j) {                  // V tile 64x128
        int f = j * 1024 + t * 4;
        int r = f >> 7, c = f & 127;
        *(f32x4*)&sV[r][c] = *(const f32x4*)&V[(size_t)r * K_ + k0 + c];
    }
    __syncthreads();
    int tn = t >> 5;          // 0..7  -> 8 n-rows each
    int tk = t & 31;          // 0..31 -> 4 k-cols each
    float acc[8][4] = {};
    for (int r = 0; r < R_; ++r) {
        f32x4 vv = *(const f32x4*)&sV[r][tk * 4];
#pragma unroll
        for (int a = 0; a < 8; ++a) {
            float u = sUS[tn * 8 + a][r];
#pragma unroll
            for (int c = 0; c < 4; ++c) acc[a][c] += u * vv[c];
        }
    }
#pragma unroll
    for (int a = 0; a < 8; ++a) {
        int n = n0 + tn * 8 + a;
        int k = k0 + tk * 4;
        f32x4 wmv = *(const f32x4*)&WM[(size_t)n * K_ + k];
        s16x4 h4, l4;
#pragma unroll
        for (int c = 0; c < 4; ++c) {
            float w = wmv[c] + acc[a][c];
            ushort_t h = f32_to_bf16_rne(w);
            h4[c] = (short)h;
            l4[c] = (short)f32_to_bf16_rne(w - bf16_to_f32(h));
        }
        *(s16x4*)&hiW[(size_t)n * K_ + k] = h4;
        *(s16x4*)&loW[(size_t)n * K_ + k] = l4;
    }
}

// ---------- prep 3: x -> planar hiA, loA (bf16) ----------
__global__ __launch_bounds__(256) void k_split_x(const float* __restrict__ X,
                                                 ushort_t* __restrict__ hiA,
                                                 ushort_t* __restrict__ loA) {
    size_t i = ((size_t)blockIdx.x * 256 + threadIdx.x) * 8;
    f32x4 a = *(const f32x4*)&X[i];
    f32x4 b = *(const f32x4*)&X[i + 4];
    bf16x8 h, l;
#pragma unroll
    for (int j = 0; j < 4; ++j) {
        ushort_t ha = f32_to_bf16_rne(a[j]);
        ushort_t hb = f32_to_bf16_rne(b[j]);
        h[j]     = (short)ha;
        h[4 + j] = (short)hb;
        l[j]     = (short)f32_to_bf16_rne(a[j] - bf16_to_f32(ha));
        l[4 + j] = (short)f32_to_bf16_rne(b[j] - bf16_to_f32(hb));
    }
    *(bf16x8*)&hiA[i] = h;
    *(bf16x8*)&loA[i] = l;
}

// ---------- main GEMM: out = hiA@hiW^T + loA@hiW^T + hiA@loW^T + bias ----------
// 3 planar bf16 segments, 128x128 tile, BK=64, 4 waves (2x2), m97 structure
template <bool PRESPLIT>
__global__ __launch_bounds__(256, 2) void k_gemm(const ushort_t* __restrict__ hiA,
                                                 const ushort_t* __restrict__ loA,
                                                 const float* __restrict__ X,
                                                 const ushort_t* __restrict__ hiW,
                                                 const ushort_t* __restrict__ loW,
                                                 const float* __restrict__ bias,
                                                 float* __restrict__ out) {
    __shared__ __align__(16) ushort_t lA[128 * 64];
    __shared__ __align__(16) ushort_t lB[128 * 64];

    // XCD-bijective swizzle (gridDim.x = 4096, divisible by 8)
    int bid = blockIdx.x;
    int cpx = gridDim.x >> 3;
    int wg  = (bid & 7) * cpx + (bid >> 3);
    constexpr int NBN = N_ / 128;                 // 32
    int m0 = (wg / NBN) * 128;
    int n0 = (wg % NBN) * 128;

    int tid  = threadIdx.x;
    int lane = tid & 63;
    int w    = tid >> 6;
    int wr   = w >> 1, wc = w & 1;                // 2x2 waves, each 64x64 out
    int fr   = lane & 15;
    int fq   = lane >> 4;

    f32x4 acc[4][4] = {};

    for (int seg = 0; seg < 3; ++seg) {
        const ushort_t* Bs = (seg == 2) ? loW : hiW;
        for (int kt = 0; kt < K_ / 64; ++kt) {
            int k0 = kt * 64;
            // stage B tile (128 n-rows x 64 k) via async global->LDS, 16B/lane
#pragma unroll
            for (int j = 0; j < 4; ++j) {
                int f = j * 2048 + tid * 8;       // ushort index in tile
                int row = f >> 6, col = f & 63;
                async_cp16(&Bs[(size_t)(n0 + row) * K_ + k0 + col], &lB[f]);
            }
            // stage A tile
            if constexpr (PRESPLIT) {
                const ushort_t* As = (seg == 1) ? loA : hiA;
#pragma unroll
                for (int j = 0; j < 4; ++j) {
                    int f = j * 2048 + tid * 8;
                    int row = f >> 6, col = f & 63;
                    async_cp16(&As[(size_t)(m0 + row) * K_ + k0 + col], &lA[f]);
                }
            } else {
                // split x in-register (hi for seg 0/2, lo for seg 1)
                bool wantLo = (seg == 1);
#pragma unroll
                for (int j = 0; j < 4; ++j) {
                    int f = j * 2048 + tid * 8;   // bf16 elem index in 128x64 tile
                    int row = f >> 6, c = f & 63;
                    const float* xp = &X[(size_t)(m0 + row) * K_ + k0 + c];
                    f32x4 x0 = *(const f32x4*)xp;
                    f32x4 x1 = *(const f32x4*)(xp + 4);
                    bf16x8 o;
#pragma unroll
                    for (int e = 0; e < 4; ++e) {
                        ushort_t h0 = f32_to_bf16_rne(x0[e]);
                        ushort_t h1 = f32_to_bf16_rne(x1[e]);
                        o[e]     = (short)(wantLo ? f32_to_bf16_rne(x0[e] - bf16_to_f32(h0)) : h0);
                        o[4 + e] = (short)(wantLo ? f32_to_bf16_rne(x1[e] - bf16_to_f32(h1)) : h1);
                    }
                    *(bf16x8*)&lA[f] = o;
                }
            }
            __syncthreads();
#pragma unroll
            for (int ks = 0; ks < 2; ++ks) {
                bf16x8 af[4], bfv[4];
#pragma unroll
                for (int i = 0; i < 4; ++i) {
                    af[i]  = *(const bf16x8*)&lA[(wr * 64 + i * 16 + fr) * 64 + ks * 32 + fq * 8];
                    bfv[i] = *(const bf16x8*)&lB[(wc * 64 + i * 16 + fr) * 64 + ks * 32 + fq * 8];
                }
#pragma unroll
                for (int i = 0; i < 4; ++i)
#pragma unroll
                    for (int j = 0; j < 4; ++j)
                        acc[i][j] = __builtin_amdgcn_mfma_f32_16x16x32_bf16(af[i], bfv[j], acc[i][j], 0, 0, 0);
            }
            __syncthreads();
        }
    }

    // epilogue: C/D layout col=lane&15, row=(lane>>4)*4+reg  [m89]
    float bcol[4];
#pragma unroll
    for (int j = 0; j < 4; ++j) bcol[j] = bias[n0 + wc * 64 + j * 16 + fr];
#pragma unroll
    for (int i = 0; i < 4; ++i) {
        int gm = m0 + wr * 64 + i * 16 + fq * 4;
#pragma unroll
        for (int j = 0; j < 4; ++j) {
            int gn = n0 + wc * 64 + j * 16 + fr;
#pragma unroll
            for (int r2 = 0; r2 < 4; ++r2)
                out[(size_t)(gm + r2) * N_ + gn] = acc[i][j][r2] + bcol[j];
        }
    }
}

// ---------- ws-free correct fallback (fp32 vector; slow, insurance only) ----------
__global__ __launch_bounds__(256) void k_naive(const float* __restrict__ X,
                                               const float* __restrict__ WM,
                                               const float* __restrict__ U,
                                               const float* __restrict__ S,
                                               const float* __restrict__ V,
                                               const float* __restrict__ bias,
                                               float* __restrict__ out) {
    __shared__ __align__(16) float sX[64][68];
    __shared__ __align__(16) float sW[64][68];
    __shared__ __align__(16) float sV[64][68];
    int t = threadIdx.x;
    int m0 = (blockIdx.x >> 6) * 64;
    int n0 = (blockIdx.x & 63) * 64;
    int tm = t >> 4, tn = t & 15;
    float acc[4][4] = {}, pacc[4][4] = {};
    for (int kc = 0; kc < K_ / 64; ++kc) {
        __syncthreads();
#pragma unroll
        for (int j = 0; j < 4; ++j) {
            int f = j * 1024 + t * 4;
            int r = f >> 6, c = f & 63;
            *(f32x4*)&sX[r][c] = *(const f32x4*)&X[(size_t)(m0 + r) * K_ + kc * 64 + c];
            *(f32x4*)&sW[r][c] = *(const f32x4*)&WM[(size_t)(n0 + r) * K_ + kc * 64 + c];
            *(f32x4*)&sV[r][c] = *(const f32x4*)&V[(size_t)r * K_ + kc * 64 + c];
        }
        __syncthreads();
        for (int k4 = 0; k4 < 16; ++k4) {
            f32x4 xa[4], wb[4], vb[4];
#pragma unroll
            for (int a = 0; a < 4; ++a) xa[a] = *(const f32x4*)&sX[tm * 4 + a][k4 * 4];
#pragma unroll
            for (int b = 0; b < 4; ++b) {
                wb[b] = *(const f32x4*)&sW[tn * 4 + b][k4 * 4];
                vb[b] = *(const f32x4*)&sV[tn * 4 + b][k4 * 4];
            }
#pragma unroll
            for (int a = 0; a < 4; ++a)
#pragma unroll
                for (int b = 0; b < 4; ++b)
#pragma unroll
                    for (int e = 0; e < 4; ++e) {
                        acc[a][b]  += xa[a][e] * wb[b][e];
                        pacc[a][b] += xa[a][e] * vb[b][e];
                    }
        }
    }
    __syncthreads();
#pragma unroll
    for (int j = 0; j < 4; ++j) {       // US into sV
        int f = j * 1024 + t * 4;
        int nl = f >> 6, r = f & 63;
        f32x4 uu = *(const f32x4*)&U[(size_t)(n0 + nl) * R_ + r];
        f32x4 ss = *(const f32x4*)&S[r];
        f32x4 us = uu * ss;
        *(f32x4*)&sV[nl][r] = us;
    }
#pragma unroll
    for (int a = 0; a < 4; ++a)
#pragma unroll
        for (int b = 0; b < 4; ++b) sW[tm * 4 + a][tn * 4 + b] = pacc[a][b];
    __syncthreads();
#pragma unroll
    for (int a = 0; a < 4; ++a)
#pragma unroll
        for (int b = 0; b < 4; ++b) {
            float s2 = acc[a][b];
            for (int r = 0; r < R_; ++r) s2 += sW[tm * 4 + a][r] * sV[tn * 4 + b][r];
            out[(size_t)(m0 + tm * 4 + a) * N_ + n0 + tn * 4 + b] = s2 + bias[n0 + tn * 4 + b];
        }
}

extern "C" void kernel_launch(void* const* d_in, const int* in_sizes, int n_in,
                              void* d_out, int out_size, void* d_ws, size_t ws_size,
                              hipStream_t stream) {
    const float* x    = (const float*)d_in[0];
    const float* wm   = (const float*)d_in[1];
    const float* U    = (const float*)d_in[2];
    const float* S    = (const float*)d_in[3];
    const float* V    = (const float*)d_in[4];
    const float* bias = (const float*)d_in[5];
    float* out = (float*)d_out;

    const size_t szA  = (size_t)M_ * K_ * 2;   // 128 MiB per planar x-split buffer
    const size_t szW  = (size_t)N_ * K_ * 2;   //  32 MiB per planar W-split buffer
    const size_t szUS = (size_t)N_ * R_ * 4;   //   1 MiB

    if (ws_size >= 2 * szA + 2 * szW + szUS) {
        ushort_t* hiA = (ushort_t*)d_ws;
        ushort_t* loA = (ushort_t*)((char*)d_ws + szA);
        ushort_t* hiW = (ushort_t*)((char*)d_ws + 2 * szA);
        ushort_t* loW = (ushort_t*)((char*)d_ws + 2 * szA + szW);
        float*    US  = (float*)((char*)d_ws + 2 * szA + 2 * szW);
        k_fold_us<<<dim3((N_ * R_ + 255) / 256), dim3(256), 0, stream>>>(U, S, US);
        k_fuse_w<<<dim3((N_ / 64) * (K_ / 128)), dim3(256), 0, stream>>>(wm, US, V, hiW, loW);
        k_split_x<<<dim3(M_ * K_ / 2048), dim3(256), 0, stream>>>(x, hiA, loA);
        k_gemm<true><<<dim3((M_ / 128) * (N_ / 128)), dim3(256), 0, stream>>>(
            hiA, loA, x, hiW, loW, bias, out);
    } else if (ws_size >= 2 * szW + szUS) {
        ushort_t* hiW = (ushort_t*)d_ws;
        ushort_t* loW = (ushort_t*)((char*)d_ws + szW);
        float*    US  = (float*)((char*)d_ws + 2 * szW);
        k_fold_us<<<dim3((N_ * R_ + 255) / 256), dim3(256), 0, stream>>>(U, S, US);
        k_fuse_w<<<dim3((N_ / 64) * (K_ / 128)), dim3(256), 0, stream>>>(wm, US, V, hiW, loW);
        k_gemm<false><<<dim3((M_ / 128) * (N_ / 128)), dim3(256), 0, stream>>>(
            nullptr, nullptr, x, hiW, loW, bias, out);
    } else {
        k_naive<<<dim3((M_ / 64) * (N_ / 64)), dim3(256), 0, stream>>>(x, wm, U, S, V, bias, out);
    }
}

// Round 3
// 2142.480 us; speedup vs baseline: 1.1677x; 1.1677x over previous
//
#include <hip/hip_runtime.h>
#include <hip/hip_bf16.h>
#include <stdint.h>

#define DI __device__ __forceinline__

typedef __attribute__((ext_vector_type(4))) float f32x4;
typedef __attribute__((ext_vector_type(8))) short bf16x8;   // 8 bf16 = 4 VGPR (MFMA A/B frag)
typedef __attribute__((ext_vector_type(4))) short s16x4;

typedef unsigned short ushort_t;

constexpr int M_ = 16384;   // B*T
constexpr int N_ = 4096;    // OUT
constexpr int K_ = 4096;    // IN
constexpr int R_ = 64;

// big-tile GEMM geometry
constexpr int BM = 256, BN = 256, BK = 64;
constexpr int NSEG = 3;
constexpr int NT_SEG = K_ / BK;          // 64 K-tiles per segment
constexpr int TOT_T = NSEG * NT_SEG;     // 192 total K-tiles

// ---------- bf16 split helpers ----------
DI ushort_t f32_to_bf16_rne(float f) {
    unsigned u = __builtin_bit_cast(unsigned, f);
    u += 0x7FFFu + ((u >> 16) & 1u);           // round-nearest-even
    return (ushort_t)(u >> 16);
}
DI float bf16_to_f32(ushort_t h) {
    return __builtin_bit_cast(float, (unsigned)h << 16);
}

DI void async_cp16(const void* g, void* l) {
    __builtin_amdgcn_global_load_lds(
        (const __attribute__((address_space(1))) unsigned*)g,
        (__attribute__((address_space(3))) unsigned*)l, 16, 0, 0);
}

// ---------- prep 1: US[n][r] = U[n][r] * S[r] ----------
__global__ __launch_bounds__(256) void k_fold_us(const float* __restrict__ U,
                                                 const float* __restrict__ S,
                                                 float* __restrict__ US) {
    int i = blockIdx.x * 256 + threadIdx.x;
    if (i < N_ * R_) US[i] = U[i] * S[i & (R_ - 1)];
}

// ---------- prep 2: W = weight_main + US @ V  ->  planar hiW, loW (bf16) ----------
__global__ __launch_bounds__(256) void k_fuse_w(const float* __restrict__ WM,
                                                const float* __restrict__ US,
                                                const float* __restrict__ V,
                                                ushort_t* __restrict__ hiW,
                                                ushort_t* __restrict__ loW) {
    __shared__ __align__(16) float sUS[64][68];    // padded rows
    __shared__ __align__(16) float sV[64][128];
    int t = threadIdx.x;
    int n0 = (blockIdx.x >> 5) * 64;
    int k0 = (blockIdx.x & 31) * 128;
#pragma unroll
    for (int j = 0; j < 4; ++j) {                  // US tile 64x64
        int f = j * 1024 + t * 4;
        int r = f >> 6, c = f & 63;
        *(f32x4*)&sUS[r][c] = *(const f32x4*)&US[(size_t)(n0 + r) * R_ + c];
    }
#pragma unroll
    for (int j = 0; j < 8; ++j) {                  // V tile 64x128
        int f = j * 1024 + t * 4;
        int r = f >> 7, c = f & 127;
        *(f32x4*)&sV[r][c] = *(const f32x4*)&V[(size_t)r * K_ + k0 + c];
    }
    __syncthreads();
    int tn = t >> 5;          // 0..7  -> 8 n-rows each
    int tk = t & 31;          // 0..31 -> 4 k-cols each
    float acc[8][4] = {};
    for (int r = 0; r < R_; ++r) {
        f32x4 vv = *(const f32x4*)&sV[r][tk * 4];
#pragma unroll
        for (int a = 0; a < 8; ++a) {
            float u = sUS[tn * 8 + a][r];
#pragma unroll
            for (int c = 0; c < 4; ++c) acc[a][c] += u * vv[c];
        }
    }
#pragma unroll
    for (int a = 0; a < 8; ++a) {
        int n = n0 + tn * 8 + a;
        int k = k0 + tk * 4;
        f32x4 wmv = *(const f32x4*)&WM[(size_t)n * K_ + k];
        s16x4 h4, l4;
#pragma unroll
        for (int c = 0; c < 4; ++c) {
            float w = wmv[c] + acc[a][c];
            ushort_t h = f32_to_bf16_rne(w);
            h4[c] = (short)h;
            l4[c] = (short)f32_to_bf16_rne(w - bf16_to_f32(h));
        }
        *(s16x4*)&hiW[(size_t)n * K_ + k] = h4;
        *(s16x4*)&loW[(size_t)n * K_ + k] = l4;
    }
}

// ---------- prep 3: x -> planar hiA, loA (bf16) ----------
__global__ __launch_bounds__(256) void k_split_x(const float* __restrict__ X,
                                                 ushort_t* __restrict__ hiA,
                                                 ushort_t* __restrict__ loA) {
    size_t i = ((size_t)blockIdx.x * 256 + threadIdx.x) * 8;
    f32x4 a = *(const f32x4*)&X[i];
    f32x4 b = *(const f32x4*)&X[i + 4];
    bf16x8 h, l;
#pragma unroll
    for (int j = 0; j < 4; ++j) {
        ushort_t ha = f32_to_bf16_rne(a[j]);
        ushort_t hb = f32_to_bf16_rne(b[j]);
        h[j]     = (short)ha;
        h[4 + j] = (short)hb;
        l[j]     = (short)f32_to_bf16_rne(a[j] - bf16_to_f32(ha));
        l[4 + j] = (short)f32_to_bf16_rne(b[j] - bf16_to_f32(hb));
    }
    *(bf16x8*)&hiA[i] = h;
    *(bf16x8*)&loA[i] = l;
}

// ---------- main GEMM: 256x256 tile, BK=64, 8 waves, counted-vmcnt dbuf ----------
// out = hiA@hiW^T + loA@hiW^T + hiA@loW^T + bias  (3 planar bf16 segments)
// T2: chunk-XOR swizzle pc = c ^ (row&7) on 128B rows -> 2-way (free) ds_read_b128
//     applied source-side (linear global_load_lds dest) + read-side  [rule 21]
// T4: vmcnt(8) counted (next tile's 8 loads stay in flight); vmcnt(0) only at tail
// T5: setprio(1) around MFMA clusters
__global__ __launch_bounds__(512, 2) void k_gemm_big(const ushort_t* __restrict__ hiA,
                                                     const ushort_t* __restrict__ loA,
                                                     const ushort_t* __restrict__ hiW,
                                                     const ushort_t* __restrict__ loW,
                                                     const float* __restrict__ bias,
                                                     float* __restrict__ out) {
    __shared__ __align__(16) ushort_t lA[2][BM * BK];   // 2 x 32 KiB
    __shared__ __align__(16) ushort_t lB[2][BN * BK];   // 2 x 32 KiB  (total 128 KiB)

    // XCD-bijective swizzle; grid = 1024 = 64 m-bands x 16 n-blocks (1024 % 8 == 0)
    int bid = blockIdx.x;
    int wg  = (bid & 7) * (gridDim.x >> 3) + (bid >> 3);
    int m0  = (wg >> 4) * BM;
    int n0  = (wg & 15) * BN;

    int tid  = threadIdx.x;
    int lane = tid & 63;
    int w    = tid >> 6;
    int wr   = w >> 2;            // 0..1  (128 M-rows each)
    int wc   = w & 3;             // 0..3  (64 N-cols each)
    int fr   = lane & 15;
    int fq   = lane >> 4;

    f32x4 acc[8][4] = {};

    auto stage = [&](int tau, int bsel) {
        int seg = tau >> 6;
        const ushort_t* As = (seg == 1) ? loA : hiA;
        const ushort_t* Bs = (seg == 2) ? loW : hiW;
        int k0 = (tau & (NT_SEG - 1)) * BK;
        ushort_t* la = lA[bsel];
        ushort_t* lb = lB[bsel];
#pragma unroll
        for (int j = 0; j < 4; ++j) {             // A tile: 2048 chunks of 16B
            int ci = j * 512 + tid;
            int row = ci >> 3, pc = ci & 7;
            int lc  = pc ^ (row & 7);             // involution: source pre-swizzle
            async_cp16(&As[(size_t)(m0 + row) * K_ + k0 + lc * 8], &la[ci * 8]);
        }
#pragma unroll
        for (int j = 0; j < 4; ++j) {             // B tile
            int ci = j * 512 + tid;
            int row = ci >> 3, pc = ci & 7;
            int lc  = pc ^ (row & 7);
            async_cp16(&Bs[(size_t)(n0 + row) * K_ + k0 + lc * 8], &lb[ci * 8]);
        }
    };

    auto compute = [&](int bsel) {
        const ushort_t* la = lA[bsel];
        const ushort_t* lb = lB[bsel];
#pragma unroll
        for (int ks = 0; ks < 2; ++ks) {
            bf16x8 af[8], bf[4];
#pragma unroll
            for (int i = 0; i < 8; ++i) {
                int row = wr * 128 + i * 16 + fr;
                af[i] = *(const bf16x8*)&la[row * 64 + (((ks * 4 + fq) ^ (row & 7)) << 3)];
            }
#pragma unroll
            for (int j = 0; j < 4; ++j) {
                int row = wc * 64 + j * 16 + fr;
                bf[j] = *(const bf16x8*)&lb[row * 64 + (((ks * 4 + fq) ^ (row & 7)) << 3)];
            }
            __builtin_amdgcn_s_setprio(1);
#pragma unroll
            for (int i = 0; i < 8; ++i)
#pragma unroll
                for (int j = 0; j < 4; ++j)
                    acc[i][j] = __builtin_amdgcn_mfma_f32_16x16x32_bf16(af[i], bf[j], acc[i][j], 0, 0, 0);
            __builtin_amdgcn_s_setprio(0);
        }
    };

    stage(0, 0);
    for (int tau = 0; tau < TOT_T - 1; ++tau) {
        stage(tau + 1, (tau + 1) & 1);
        asm volatile("s_waitcnt vmcnt(8)" ::: "memory");   // counted: stage(tau) landed
        __builtin_amdgcn_s_barrier();
        compute(tau & 1);
        asm volatile("" ::: "memory");
        __builtin_amdgcn_s_barrier();                      // protect buf before next overwrite
        asm volatile("" ::: "memory");
    }
    asm volatile("s_waitcnt vmcnt(0)" ::: "memory");       // tail drain (only one)
    __builtin_amdgcn_s_barrier();
    compute((TOT_T - 1) & 1);

    // epilogue: C/D layout col=lane&15, row=(lane>>4)*4+reg  [m89]
    float bcol[4];
#pragma unroll
    for (int j = 0; j < 4; ++j) bcol[j] = bias[n0 + wc * 64 + j * 16 + fr];
#pragma unroll
    for (int i = 0; i < 8; ++i) {
        int gm = m0 + wr * 128 + i * 16 + fq * 4;
#pragma unroll
        for (int j = 0; j < 4; ++j) {
            int gn = n0 + wc * 64 + j * 16 + fr;
#pragma unroll
            for (int r2 = 0; r2 < 4; ++r2)
                out[(size_t)(gm + r2) * N_ + gn] = acc[i][j][r2] + bcol[j];
        }
    }
}

// ---------- tier-2 GEMM (ws fits only W): 128x128 m97 structure, in-register x split ----------
__global__ __launch_bounds__(256, 2) void k_gemm_small(const float* __restrict__ X,
                                                       const ushort_t* __restrict__ hiW,
                                                       const ushort_t* __restrict__ loW,
                                                       const float* __restrict__ bias,
                                                       float* __restrict__ out) {
    __shared__ __align__(16) ushort_t lA[128 * 64];
    __shared__ __align__(16) ushort_t lB[128 * 64];
    int bid = blockIdx.x;
    int cpx = gridDim.x >> 3;
    int wg  = (bid & 7) * cpx + (bid >> 3);
    constexpr int NBN = N_ / 128;
    int m0 = (wg / NBN) * 128;
    int n0 = (wg % NBN) * 128;
    int tid  = threadIdx.x;
    int lane = tid & 63;
    int w    = tid >> 6;
    int wr   = w >> 1, wc = w & 1;
    int fr   = lane & 15;
    int fq   = lane >> 4;
    f32x4 acc[4][4] = {};
    for (int seg = 0; seg < 3; ++seg) {
        const ushort_t* Bs = (seg == 2) ? loW : hiW;
        bool wantLo = (seg == 1);
        for (int kt = 0; kt < K_ / 64; ++kt) {
            int k0 = kt * 64;
#pragma unroll
            for (int j = 0; j < 4; ++j) {
                int f = j * 2048 + tid * 8;
                int row = f >> 6, col = f & 63;
                async_cp16(&Bs[(size_t)(n0 + row) * K_ + k0 + col], &lB[f]);
            }
#pragma unroll
            for (int j = 0; j < 4; ++j) {
                int f = j * 2048 + tid * 8;
                int row = f >> 6, c = f & 63;
                const float* xp = &X[(size_t)(m0 + row) * K_ + k0 + c];
                f32x4 x0 = *(const f32x4*)xp;
                f32x4 x1 = *(const f32x4*)(xp + 4);
                bf16x8 o;
#pragma unroll
                for (int e = 0; e < 4; ++e) {
                    ushort_t h0 = f32_to_bf16_rne(x0[e]);
                    ushort_t h1 = f32_to_bf16_rne(x1[e]);
                    o[e]     = (short)(wantLo ? f32_to_bf16_rne(x0[e] - bf16_to_f32(h0)) : h0);
                    o[4 + e] = (short)(wantLo ? f32_to_bf16_rne(x1[e] - bf16_to_f32(h1)) : h1);
                }
                *(bf16x8*)&lA[f] = o;
            }
            __syncthreads();
#pragma unroll
            for (int ks = 0; ks < 2; ++ks) {
                bf16x8 af[4], bfv[4];
#pragma unroll
                for (int i = 0; i < 4; ++i) {
                    af[i]  = *(const bf16x8*)&lA[(wr * 64 + i * 16 + fr) * 64 + ks * 32 + fq * 8];
                    bfv[i] = *(const bf16x8*)&lB[(wc * 64 + i * 16 + fr) * 64 + ks * 32 + fq * 8];
                }
#pragma unroll
                for (int i = 0; i < 4; ++i)
#pragma unroll
                    for (int j = 0; j < 4; ++j)
                        acc[i][j] = __builtin_amdgcn_mfma_f32_16x16x32_bf16(af[i], bfv[j], acc[i][j], 0, 0, 0);
            }
            __syncthreads();
        }
    }
    float bcol[4];
#pragma unroll
    for (int j = 0; j < 4; ++j) bcol[j] = bias[n0 + wc * 64 + j * 16 + fr];
#pragma unroll
    for (int i = 0; i < 4; ++i) {
        int gm = m0 + wr * 64 + i * 16 + fq * 4;
#pragma unroll
        for (int j = 0; j < 4; ++j) {
            int gn = n0 + wc * 64 + j * 16 + fr;
#pragma unroll
            for (int r2 = 0; r2 < 4; ++r2)
                out[(size_t)(gm + r2) * N_ + gn] = acc[i][j][r2] + bcol[j];
        }
    }
}

// ---------- ws-free correct fallback (fp32 vector; insurance only) ----------
__global__ __launch_bounds__(256) void k_naive(const float* __restrict__ X,
                                               const float* __restrict__ WM,
                                               const float* __restrict__ U,
                                               const float* __restrict__ S,
                                               const float* __restrict__ V,
                                               const float* __restrict__ bias,
                                               float* __restrict__ out) {
    __shared__ __align__(16) float sX[64][68];
    __shared__ __align__(16) float sW[64][68];
    __shared__ __align__(16) float sV[64][68];
    int t = threadIdx.x;
    int m0 = (blockIdx.x >> 6) * 64;
    int n0 = (blockIdx.x & 63) * 64;
    int tm = t >> 4, tn = t & 15;
    float acc[4][4] = {}, pacc[4][4] = {};
    for (int kc = 0; kc < K_ / 64; ++kc) {
        __syncthreads();
#pragma unroll
        for (int j = 0; j < 4; ++j) {
            int f = j * 1024 + t * 4;
            int r = f >> 6, c = f & 63;
            *(f32x4*)&sX[r][c] = *(const f32x4*)&X[(size_t)(m0 + r) * K_ + kc * 64 + c];
            *(f32x4*)&sW[r][c] = *(const f32x4*)&WM[(size_t)(n0 + r) * K_ + kc * 64 + c];
            *(f32x4*)&sV[r][c] = *(const f32x4*)&V[(size_t)r * K_ + kc * 64 + c];
        }
        __syncthreads();
        for (int k4 = 0; k4 < 16; ++k4) {
            f32x4 xa[4], wb[4], vb[4];
#pragma unroll
            for (int a = 0; a < 4; ++a) xa[a] = *(const f32x4*)&sX[tm * 4 + a][k4 * 4];
#pragma unroll
            for (int b = 0; b < 4; ++b) {
                wb[b] = *(const f32x4*)&sW[tn * 4 + b][k4 * 4];
                vb[b] = *(const f32x4*)&sV[tn * 4 + b][k4 * 4];
            }
#pragma unroll
            for (int a = 0; a < 4; ++a)
#pragma unroll
                for (int b = 0; b < 4; ++b)
#pragma unroll
                    for (int e = 0; e < 4; ++e) {
                        acc[a][b]  += xa[a][e] * wb[b][e];
                        pacc[a][b] += xa[a][e] * vb[b][e];
                    }
        }
    }
    __syncthreads();
#pragma unroll
    for (int j = 0; j < 4; ++j) {
        int f = j * 1024 + t * 4;
        int nl = f >> 6, r = f & 63;
        f32x4 uu = *(const f32x4*)&U[(size_t)(n0 + nl) * R_ + r];
        f32x4 ss = *(const f32x4*)&S[r];
        f32x4 us = uu * ss;
        *(f32x4*)&sV[nl][r] = us;
    }
#pragma unroll
    for (int a = 0; a < 4; ++a)
#pragma unroll
        for (int b = 0; b < 4; ++b) sW[tm * 4 + a][tn * 4 + b] = pacc[a][b];
    __syncthreads();
#pragma unroll
    for (int a = 0; a < 4; ++a)
#pragma unroll
        for (int b = 0; b < 4; ++b) {
            float s2 = acc[a][b];
            for (int r = 0; r < R_; ++r) s2 += sW[tm * 4 + a][r] * sV[tn * 4 + b][r];
            out[(size_t)(m0 + tm * 4 + a) * N_ + n0 + tn * 4 + b] = s2 + bias[n0 + tn * 4 + b];
        }
}

extern "C" void kernel_launch(void* const* d_in, const int* in_sizes, int n_in,
                              void* d_out, int out_size, void* d_ws, size_t ws_size,
                              hipStream_t stream) {
    const float* x    = (const float*)d_in[0];
    const float* wm   = (const float*)d_in[1];
    const float* U    = (const float*)d_in[2];
    const float* S    = (const float*)d_in[3];
    const float* V    = (const float*)d_in[4];
    const float* bias = (const float*)d_in[5];
    float* out = (float*)d_out;

    const size_t szA  = (size_t)M_ * K_ * 2;   // 128 MiB per planar x-split buffer
    const size_t szW  = (size_t)N_ * K_ * 2;   //  32 MiB per planar W-split buffer
    const size_t szUS = (size_t)N_ * R_ * 4;   //   1 MiB

    if (ws_size >= 2 * szA + 2 * szW + szUS) {
        ushort_t* hiA = (ushort_t*)d_ws;
        ushort_t* loA = (ushort_t*)((char*)d_ws + szA);
        ushort_t* hiW = (ushort_t*)((char*)d_ws + 2 * szA);
        ushort_t* loW = (ushort_t*)((char*)d_ws + 2 * szA + szW);
        float*    US  = (float*)((char*)d_ws + 2 * szA + 2 * szW);
        k_fold_us<<<dim3((N_ * R_ + 255) / 256), dim3(256), 0, stream>>>(U, S, US);
        k_fuse_w<<<dim3((N_ / 64) * (K_ / 128)), dim3(256), 0, stream>>>(wm, US, V, hiW, loW);
        k_split_x<<<dim3(M_ * K_ / 2048), dim3(256), 0, stream>>>(x, hiA, loA);
        k_gemm_big<<<dim3((M_ / BM) * (N_ / BN)), dim3(512), 0, stream>>>(
            hiA, loA, hiW, loW, bias, out);
    } else if (ws_size >= 2 * szW + szUS) {
        ushort_t* hiW = (ushort_t*)d_ws;
        ushort_t* loW = (ushort_t*)((char*)d_ws + szW);
        float*    US  = (float*)((char*)d_ws + 2 * szW);
        k_fold_us<<<dim3((N_ * R_ + 255) / 256), dim3(256), 0, stream>>>(U, S, US);
        k_fuse_w<<<dim3((N_ / 64) * (K_ / 128)), dim3(256), 0, stream>>>(wm, US, V, hiW, loW);
        k_gemm_small<<<dim3((M_ / 128) * (N_ / 128)), dim3(256), 0, stream>>>(
            x, hiW, loW, bias, out);
    } else {
        k_naive<<<dim3((M_ / 64) * (N_ / 64)), dim3(256), 0, stream>>>(x, wm, U, S, V, bias, out);
    }
}

// Round 4
// 1872.958 us; speedup vs baseline: 1.3357x; 1.1439x over previous
//
#include <hip/hip_runtime.h>
#include <hip/hip_bf16.h>
#include <stdint.h>

#define DI __device__ __forceinline__

typedef __attribute__((ext_vector_type(4))) float f32x4;
typedef __attribute__((ext_vector_type(8))) short bf16x8;   // 8 bf16 = 4 VGPR (MFMA A/B frag)
typedef __attribute__((ext_vector_type(4))) short s16x4;

typedef unsigned short ushort_t;

constexpr int M_ = 16384;   // B*T
constexpr int N_ = 4096;    // OUT
constexpr int K_ = 4096;    // IN
constexpr int R_ = 64;

// big-tile GEMM geometry
constexpr int BM = 256, BN = 256, BK = 64;
constexpr int NSEG = 3;
constexpr int NT_SEG = K_ / BK;          // 64 K-tiles per segment
constexpr int TOT_T = NSEG * NT_SEG;     // 192 total K-tiles (even; NIT = 96)

// ---------- bf16 split helpers ----------
DI ushort_t f32_to_bf16_rne(float f) {
    unsigned u = __builtin_bit_cast(unsigned, f);
    u += 0x7FFFu + ((u >> 16) & 1u);           // round-nearest-even
    return (ushort_t)(u >> 16);
}
DI float bf16_to_f32(ushort_t h) {
    return __builtin_bit_cast(float, (unsigned)h << 16);
}

DI void async_cp16(const void* g, void* l) {
    __builtin_amdgcn_global_load_lds(
        (const __attribute__((address_space(1))) unsigned*)g,
        (__attribute__((address_space(3))) unsigned*)l, 16, 0, 0);
}

// barrier with compiler memory fences (raw s_barrier is not a guaranteed
// code-motion barrier for memory ops; the empty asm pins VMEM/DS ordering)
#define BAR() do { asm volatile("" ::: "memory"); \
                   __builtin_amdgcn_s_barrier(); \
                   asm volatile("" ::: "memory"); } while (0)
// phase mid-point: barrier, drain ds_reads, pin (rule #18), boost prio
#define MID() do { BAR(); \
                   asm volatile("s_waitcnt lgkmcnt(0)" ::: "memory"); \
                   __builtin_amdgcn_sched_barrier(0); \
                   __builtin_amdgcn_s_setprio(1); } while (0)
#define ENDP() do { __builtin_amdgcn_s_setprio(0); BAR(); } while (0)

// ---------- prep 1: US[n][r] = U[n][r] * S[r] ----------
__global__ __launch_bounds__(256) void k_fold_us(const float* __restrict__ U,
                                                 const float* __restrict__ S,
                                                 float* __restrict__ US) {
    int i = blockIdx.x * 256 + threadIdx.x;
    if (i < N_ * R_) US[i] = U[i] * S[i & (R_ - 1)];
}

// ---------- prep 2: W = weight_main + US @ V  ->  planar hiW, loW (bf16) ----------
__global__ __launch_bounds__(256) void k_fuse_w(const float* __restrict__ WM,
                                                const float* __restrict__ US,
                                                const float* __restrict__ V,
                                                ushort_t* __restrict__ hiW,
                                                ushort_t* __restrict__ loW) {
    __shared__ __align__(16) float sUS[64][68];    // padded rows
    __shared__ __align__(16) float sV[64][128];
    int t = threadIdx.x;
    int n0 = (blockIdx.x >> 5) * 64;
    int k0 = (blockIdx.x & 31) * 128;
#pragma unroll
    for (int j = 0; j < 4; ++j) {                  // US tile 64x64
        int f = j * 1024 + t * 4;
        int r = f >> 6, c = f & 63;
        *(f32x4*)&sUS[r][c] = *(const f32x4*)&US[(size_t)(n0 + r) * R_ + c];
    }
#pragma unroll
    for (int j = 0; j < 8; ++j) {                  // V tile 64x128
        int f = j * 1024 + t * 4;
        int r = f >> 7, c = f & 127;
        *(f32x4*)&sV[r][c] = *(const f32x4*)&V[(size_t)r * K_ + k0 + c];
    }
    __syncthreads();
    int tn = t >> 5;
    int tk = t & 31;
    float acc[8][4] = {};
    for (int r = 0; r < R_; ++r) {
        f32x4 vv = *(const f32x4*)&sV[r][tk * 4];
#pragma unroll
        for (int a = 0; a < 8; ++a) {
            float u = sUS[tn * 8 + a][r];
#pragma unroll
            for (int c = 0; c < 4; ++c) acc[a][c] += u * vv[c];
        }
    }
#pragma unroll
    for (int a = 0; a < 8; ++a) {
        int n = n0 + tn * 8 + a;
        int k = k0 + tk * 4;
        f32x4 wmv = *(const f32x4*)&WM[(size_t)n * K_ + k];
        s16x4 h4, l4;
#pragma unroll
        for (int c = 0; c < 4; ++c) {
            float w = wmv[c] + acc[a][c];
            ushort_t h = f32_to_bf16_rne(w);
            h4[c] = (short)h;
            l4[c] = (short)f32_to_bf16_rne(w - bf16_to_f32(h));
        }
        *(s16x4*)&hiW[(size_t)n * K_ + k] = h4;
        *(s16x4*)&loW[(size_t)n * K_ + k] = l4;
    }
}

// ---------- prep 3: x -> planar hiA, loA (bf16) ----------
__global__ __launch_bounds__(256) void k_split_x(const float* __restrict__ X,
                                                 ushort_t* __restrict__ hiA,
                                                 ushort_t* __restrict__ loA) {
    size_t i = ((size_t)blockIdx.x * 256 + threadIdx.x) * 8;
    f32x4 a = *(const f32x4*)&X[i];
    f32x4 b = *(const f32x4*)&X[i + 4];
    bf16x8 h, l;
#pragma unroll
    for (int j = 0; j < 4; ++j) {
        ushort_t ha = f32_to_bf16_rne(a[j]);
        ushort_t hb = f32_to_bf16_rne(b[j]);
        h[j]     = (short)ha;
        h[4 + j] = (short)hb;
        l[j]     = (short)f32_to_bf16_rne(a[j] - bf16_to_f32(ha));
        l[4 + j] = (short)f32_to_bf16_rne(b[j] - bf16_to_f32(hb));
    }
    *(bf16x8*)&hiA[i] = h;
    *(bf16x8*)&loA[i] = l;
}

// ---------- main GEMM: 256x256, BK=64, 8 waves, m201-style 8-phase schedule ----------
// out = hiA@hiW^T + loA@hiW^T + hiA@loW^T + bias  (3 planar bf16 segments)
//
// Iteration i computes K-tiles e=2i (buf0, phases 1-4) and o=2i+1 (buf1, phases 5-8).
// Per-wave tile 128x64; quadrants Q1=(i0-3,j0-1) Q2=(i0-3,j2-3) Q3=(i4-7,j2-3)
// Q4=(i4-7,j0-1) -> 16 MFMA each, B-frag regs reused across phases.
//
// Half-tile (128 rows x 64 cols = 16KB = 2 loads/thread) stage schedule, with the
// barrier after which the target region is provably dead:
//   ph1: A0(buf1)<-tile 2i+1  [dead since ph7 end, iter i-1]   read ph5..7
//   ph2: A1(buf1)<-tile 2i+1  [dead since ph7 end, iter i-1]
//   ph3: B0(buf0)<-tile 2i+2  [B(buf0) reads end ph2]          read ph1.. iter i+1
//   ph4: B1(buf0)<-tile 2i+2
//   ph5: A0(buf0)<-tile 2i+2  [A(buf0) reads end ph3]
//   ph6: A1(buf0)<-tile 2i+2
//   ph7: B0(buf1)<-tile 2i+3  [B(buf1) reads end ph6]          read ph5.. iter i+1
//   ph8: B1(buf1)<-tile 2i+3
// Verify (counted, never 0 in loop): vmcnt(4) at ph4 covers tile 2i+1 (newer: ph3+ph4
// stages = 4 loads); vmcnt(4) at ph8 covers tile 2i+2 (newer: ph7+ph8 = 4 loads).
// Prologue: tile0 full + tile1 B (12 loads), vmcnt(4) -> tile0 landed.
// Last iteration stages wrap-tiles (idx % TOT_T): valid addrs, dead regions, never read.
__global__ __launch_bounds__(512, 2) void k_gemm_8ph(const ushort_t* __restrict__ hiA,
                                                     const ushort_t* __restrict__ loA,
                                                     const ushort_t* __restrict__ hiW,
                                                     const ushort_t* __restrict__ loW,
                                                     const float* __restrict__ bias,
                                                     float* __restrict__ out) {
    __shared__ __align__(16) ushort_t lA[2][BM * BK];   // 2 x 32 KiB
    __shared__ __align__(16) ushort_t lB[2][BN * BK];   // 2 x 32 KiB  (128 KiB total)

    // XCD-bijective swizzle; grid = 1024 (divisible by 8)
    int bid = blockIdx.x;
    int wg  = (bid & 7) * (gridDim.x >> 3) + (bid >> 3);
    int m0  = (wg >> 4) * BM;
    int n0  = (wg & 15) * BN;

    int tid  = threadIdx.x;
    int lane = tid & 63;
    int w    = tid >> 6;
    int wr   = w >> 2;            // 0..1  (128 M-rows each)
    int wc   = w & 3;             // 0..3  (64 N-cols each)
    int fr   = lane & 15;
    int fq   = lane >> 4;

    f32x4 acc[8][4] = {};

    // stage one half-tile; chunk-XOR swizzle on the GLOBAL source (linear LDS dest)
    auto stageA = [&](int tau, int h) {
        int seg = tau >> 6;
        const ushort_t* As = (seg == 1) ? loA : hiA;
        int k0 = (tau & (NT_SEG - 1)) * BK;
        ushort_t* dst = &lA[tau & 1][h * (128 * 64)];
#pragma unroll
        for (int j = 0; j < 2; ++j) {
            int ci  = j * 512 + tid;          // 16B chunk id: row=ci>>3, chunk=ci&7
            int row = ci >> 3, pc = ci & 7;
            int lc  = pc ^ (row & 7);         // involution
            async_cp16(&As[(size_t)(m0 + h * 128 + row) * K_ + k0 + lc * 8], &dst[ci * 8]);
        }
    };
    auto stageB = [&](int tau, int h) {
        int seg = tau >> 6;
        const ushort_t* Bs = (seg == 2) ? loW : hiW;
        int k0 = (tau & (NT_SEG - 1)) * BK;
        ushort_t* dst = &lB[tau & 1][h * (128 * 64)];
#pragma unroll
        for (int j = 0; j < 2; ++j) {
            int ci  = j * 512 + tid;
            int row = ci >> 3, pc = ci & 7;
            int lc  = pc ^ (row & 7);
            async_cp16(&Bs[(size_t)(n0 + h * 128 + row) * K_ + k0 + lc * 8], &dst[ci * 8]);
        }
    };
    auto rdA = [&](const ushort_t* la, int i, int ks) -> bf16x8 {
        int row = wr * 128 + i * 16 + fr;
        return *(const bf16x8*)&la[row * 64 + (((ks * 4 + fq) ^ (row & 7)) << 3)];
    };
    auto rdB = [&](const ushort_t* lb, int j, int ks) -> bf16x8 {
        int row = wc * 64 + j * 16 + fr;
        return *(const bf16x8*)&lb[row * 64 + (((ks * 4 + fq) ^ (row & 7)) << 3)];
    };

    bf16x8 aF[4][2];   // A frags (i-block of 4), reloaded per half
    bf16x8 bE[2][2];   // B0-1 frags, live ph1->ph4 (and ph5->ph8)
    bf16x8 bO[2][2];   // B2-3 frags, live ph2->ph3 (and ph6->ph7)

    // ---- prologue: tile0 (full) -> buf0; tile1 B-halves -> buf1; 12 loads
    stageB(0, 0); stageB(0, 1); stageA(0, 0); stageA(0, 1);
    stageB(1, 0); stageB(1, 1);
    asm volatile("s_waitcnt vmcnt(4)" ::: "memory");   // oldest 8 = tile0 landed
    BAR();

    const ushort_t* la0 = lA[0]; const ushort_t* lb0 = lB[0];
    const ushort_t* la1 = lA[1]; const ushort_t* lb1 = lB[1];

    constexpr int NIT = TOT_T / 2;   // 96
    for (int it = 0; it < NIT; ++it) {
        int to = 2 * it + 1;                 // odd tile (buf1), computed ph5-8
        int ne = (2 * it + 2) % TOT_T;       // next even tile -> buf0
        int no = (2 * it + 3) % TOT_T;       // next odd tile  -> buf1

        // ---- ph1: Q1 (i0-3, j0-1) on buf0
#pragma unroll
        for (int i = 0; i < 4; ++i) { aF[i][0] = rdA(la0, i, 0); aF[i][1] = rdA(la0, i, 1); }
#pragma unroll
        for (int j = 0; j < 2; ++j) { bE[j][0] = rdB(lb0, j, 0); bE[j][1] = rdB(lb0, j, 1); }
        stageA(to, 0);
        asm volatile("s_waitcnt lgkmcnt(8)" ::: "memory");
        MID();
#pragma unroll
        for (int i = 0; i < 4; ++i)
#pragma unroll
            for (int j = 0; j < 2; ++j)
#pragma unroll
                for (int ks = 0; ks < 2; ++ks)
                    acc[i][j] = __builtin_amdgcn_mfma_f32_16x16x32_bf16(aF[i][ks], bE[j][ks], acc[i][j], 0, 0, 0);
        ENDP();

        // ---- ph2: Q2 (i0-3, j2-3)
#pragma unroll
        for (int j = 0; j < 2; ++j) { bO[j][0] = rdB(lb0, 2 + j, 0); bO[j][1] = rdB(lb0, 2 + j, 1); }
        stageA(to, 1);
        MID();
#pragma unroll
        for (int i = 0; i < 4; ++i)
#pragma unroll
            for (int j = 0; j < 2; ++j)
#pragma unroll
                for (int ks = 0; ks < 2; ++ks)
                    acc[i][2 + j] = __builtin_amdgcn_mfma_f32_16x16x32_bf16(aF[i][ks], bO[j][ks], acc[i][2 + j], 0, 0, 0);
        ENDP();

        // ---- ph3: Q3 (i4-7, j2-3)
#pragma unroll
        for (int i = 0; i < 4; ++i) { aF[i][0] = rdA(la0, 4 + i, 0); aF[i][1] = rdA(la0, 4 + i, 1); }
        stageB(ne, 0);
        MID();
#pragma unroll
        for (int i = 0; i < 4; ++i)
#pragma unroll
            for (int j = 0; j < 2; ++j)
#pragma unroll
                for (int ks = 0; ks < 2; ++ks)
                    acc[4 + i][2 + j] = __builtin_amdgcn_mfma_f32_16x16x32_bf16(aF[i][ks], bO[j][ks], acc[4 + i][2 + j], 0, 0, 0);
        ENDP();

        // ---- ph4: Q4 (i4-7, j0-1); vmcnt checkpoint for tile `to`
        stageB(ne, 1);
        asm volatile("s_waitcnt vmcnt(4)" ::: "memory");
        MID();
#pragma unroll
        for (int i = 0; i < 4; ++i)
#pragma unroll
            for (int j = 0; j < 2; ++j)
#pragma unroll
                for (int ks = 0; ks < 2; ++ks)
                    acc[4 + i][j] = __builtin_amdgcn_mfma_f32_16x16x32_bf16(aF[i][ks], bE[j][ks], acc[4 + i][j], 0, 0, 0);
        ENDP();

        // ---- ph5: Q1 on buf1
#pragma unroll
        for (int i = 0; i < 4; ++i) { aF[i][0] = rdA(la1, i, 0); aF[i][1] = rdA(la1, i, 1); }
#pragma unroll
        for (int j = 0; j < 2; ++j) { bE[j][0] = rdB(lb1, j, 0); bE[j][1] = rdB(lb1, j, 1); }
        stageA(ne, 0);
        asm volatile("s_waitcnt lgkmcnt(8)" ::: "memory");
        MID();
#pragma unroll
        for (int i = 0; i < 4; ++i)
#pragma unroll
            for (int j = 0; j < 2; ++j)
#pragma unroll
                for (int ks = 0; ks < 2; ++ks)
                    acc[i][j] = __builtin_amdgcn_mfma_f32_16x16x32_bf16(aF[i][ks], bE[j][ks], acc[i][j], 0, 0, 0);
        ENDP();

        // ---- ph6: Q2
#pragma unroll
        for (int j = 0; j < 2; ++j) { bO[j][0] = rdB(lb1, 2 + j, 0); bO[j][1] = rdB(lb1, 2 + j, 1); }
        stageA(ne, 1);
        MID();
#pragma unroll
        for (int i = 0; i < 4; ++i)
#pragma unroll
            for (int j = 0; j < 2; ++j)
#pragma unroll
                for (int ks = 0; ks < 2; ++ks)
                    acc[i][2 + j] = __builtin_amdgcn_mfma_f32_16x16x32_bf16(aF[i][ks], bO[j][ks], acc[i][2 + j], 0, 0, 0);
        ENDP();

        // ---- ph7: Q3
#pragma unroll
        for (int i = 0; i < 4; ++i) { aF[i][0] = rdA(la1, 4 + i, 0); aF[i][1] = rdA(la1, 4 + i, 1); }
        stageB(no, 0);
        MID();
#pragma unroll
        for (int i = 0; i < 4; ++i)
#pragma unroll
            for (int j = 0; j < 2; ++j)
#pragma unroll
                for (int ks = 0; ks < 2; ++ks)
                    acc[4 + i][2 + j] = __builtin_amdgcn_mfma_f32_16x16x32_bf16(aF[i][ks], bO[j][ks], acc[4 + i][2 + j], 0, 0, 0);
        ENDP();

        // ---- ph8: Q4; vmcnt checkpoint for tile `ne`
        stageB(no, 1);
        asm volatile("s_waitcnt vmcnt(4)" ::: "memory");
        MID();
#pragma unroll
        for (int i = 0; i < 4; ++i)
#pragma unroll
            for (int j = 0; j < 2; ++j)
#pragma unroll
                for (int ks = 0; ks < 2; ++ks)
                    acc[4 + i][j] = __builtin_amdgcn_mfma_f32_16x16x32_bf16(aF[i][ks], bE[j][ks], acc[4 + i][j], 0, 0, 0);
        ENDP();
    }

    asm volatile("s_waitcnt vmcnt(0)" ::: "memory");   // drain wrap stages (old, cheap)

    // epilogue: C/D layout col=lane&15, row=(lane>>4)*4+reg  [m89]
    float bcol[4];
#pragma unroll
    for (int j = 0; j < 4; ++j) bcol[j] = bias[n0 + wc * 64 + j * 16 + fr];
#pragma unroll
    for (int i = 0; i < 8; ++i) {
        int gm = m0 + wr * 128 + i * 16 + fq * 4;
#pragma unroll
        for (int j = 0; j < 4; ++j) {
            int gn = n0 + wc * 64 + j * 16 + fr;
#pragma unroll
            for (int r2 = 0; r2 < 4; ++r2)
                out[(size_t)(gm + r2) * N_ + gn] = acc[i][j][r2] + bcol[j];
        }
    }
}

// ---------- tier-2 GEMM (ws fits only W): 128x128 m97 structure, in-register x split ----------
__global__ __launch_bounds__(256, 2) void k_gemm_small(const float* __restrict__ X,
                                                       const ushort_t* __restrict__ hiW,
                                                       const ushort_t* __restrict__ loW,
                                                       const float* __restrict__ bias,
                                                       float* __restrict__ out) {
    __shared__ __align__(16) ushort_t lA[128 * 64];
    __shared__ __align__(16) ushort_t lB[128 * 64];
    int bid = blockIdx.x;
    int cpx = gridDim.x >> 3;
    int wg  = (bid & 7) * cpx + (bid >> 3);
    constexpr int NBN = N_ / 128;
    int m0 = (wg / NBN) * 128;
    int n0 = (wg % NBN) * 128;
    int tid  = threadIdx.x;
    int lane = tid & 63;
    int w    = tid >> 6;
    int wr   = w >> 1, wc = w & 1;
    int fr   = lane & 15;
    int fq   = lane >> 4;
    f32x4 acc[4][4] = {};
    for (int seg = 0; seg < 3; ++seg) {
        const ushort_t* Bs = (seg == 2) ? loW : hiW;
        bool wantLo = (seg == 1);
        for (int kt = 0; kt < K_ / 64; ++kt) {
            int k0 = kt * 64;
#pragma unroll
            for (int j = 0; j < 4; ++j) {
                int f = j * 2048 + tid * 8;
                int row = f >> 6, col = f & 63;
                async_cp16(&Bs[(size_t)(n0 + row) * K_ + k0 + col], &lB[f]);
            }
#pragma unroll
            for (int j = 0; j < 4; ++j) {
                int f = j * 2048 + tid * 8;
                int row = f >> 6, c = f & 63;
                const float* xp = &X[(size_t)(m0 + row) * K_ + k0 + c];
                f32x4 x0 = *(const f32x4*)xp;
                f32x4 x1 = *(const f32x4*)(xp + 4);
                bf16x8 o;
#pragma unroll
                for (int e = 0; e < 4; ++e) {
                    ushort_t h0 = f32_to_bf16_rne(x0[e]);
                    ushort_t h1 = f32_to_bf16_rne(x1[e]);
                    o[e]     = (short)(wantLo ? f32_to_bf16_rne(x0[e] - bf16_to_f32(h0)) : h0);
                    o[4 + e] = (short)(wantLo ? f32_to_bf16_rne(x1[e] - bf16_to_f32(h1)) : h1);
                }
                *(bf16x8*)&lA[f] = o;
            }
            __syncthreads();
#pragma unroll
            for (int ks = 0; ks < 2; ++ks) {
                bf16x8 af[4], bfv[4];
#pragma unroll
                for (int i = 0; i < 4; ++i) {
                    af[i]  = *(const bf16x8*)&lA[(wr * 64 + i * 16 + fr) * 64 + ks * 32 + fq * 8];
                    bfv[i] = *(const bf16x8*)&lB[(wc * 64 + i * 16 + fr) * 64 + ks * 32 + fq * 8];
                }
#pragma unroll
                for (int i = 0; i < 4; ++i)
#pragma unroll
                    for (int j = 0; j < 4; ++j)
                        acc[i][j] = __builtin_amdgcn_mfma_f32_16x16x32_bf16(af[i], bfv[j], acc[i][j], 0, 0, 0);
            }
            __syncthreads();
        }
    }
    float bcol[4];
#pragma unroll
    for (int j = 0; j < 4; ++j) bcol[j] = bias[n0 + wc * 64 + j * 16 + fr];
#pragma unroll
    for (int i = 0; i < 4; ++i) {
        int gm = m0 + wr * 64 + i * 16 + fq * 4;
#pragma unroll
        for (int j = 0; j < 4; ++j) {
            int gn = n0 + wc * 64 + j * 16 + fr;
#pragma unroll
            for (int r2 = 0; r2 < 4; ++r2)
                out[(size_t)(gm + r2) * N_ + gn] = acc[i][j][r2] + bcol[j];
        }
    }
}

// ---------- ws-free correct fallback (fp32 vector; insurance only) ----------
__global__ __launch_bounds__(256) void k_naive(const float* __restrict__ X,
                                               const float* __restrict__ WM,
                                               const float* __restrict__ U,
                                               const float* __restrict__ S,
                                               const float* __restrict__ V,
                                               const float* __restrict__ bias,
                                               float* __restrict__ out) {
    __shared__ __align__(16) float sX[64][68];
    __shared__ __align__(16) float sW[64][68];
    __shared__ __align__(16) float sV[64][68];
    int t = threadIdx.x;
    int m0 = (blockIdx.x >> 6) * 64;
    int n0 = (blockIdx.x & 63) * 64;
    int tm = t >> 4, tn = t & 15;
    float acc[4][4] = {}, pacc[4][4] = {};
    for (int kc = 0; kc < K_ / 64; ++kc) {
        __syncthreads();
#pragma unroll
        for (int j = 0; j < 4; ++j) {
            int f = j * 1024 + t * 4;
            int r = f >> 6, c = f & 63;
            *(f32x4*)&sX[r][c] = *(const f32x4*)&X[(size_t)(m0 + r) * K_ + kc * 64 + c];
            *(f32x4*)&sW[r][c] = *(const f32x4*)&WM[(size_t)(n0 + r) * K_ + kc * 64 + c];
            *(f32x4*)&sV[r][c] = *(const f32x4*)&V[(size_t)r * K_ + kc * 64 + c];
        }
        __syncthreads();
        for (int k4 = 0; k4 < 16; ++k4) {
            f32x4 xa[4], wb[4], vb[4];
#pragma unroll
            for (int a = 0; a < 4; ++a) xa[a] = *(const f32x4*)&sX[tm * 4 + a][k4 * 4];
#pragma unroll
            for (int b = 0; b < 4; ++b) {
                wb[b] = *(const f32x4*)&sW[tn * 4 + b][k4 * 4];
                vb[b] = *(const f32x4*)&sV[tn * 4 + b][k4 * 4];
            }
#pragma unroll
            for (int a = 0; a < 4; ++a)
#pragma unroll
                for (int b = 0; b < 4; ++b)
#pragma unroll
                    for (int e = 0; e < 4; ++e) {
                        acc[a][b]  += xa[a][e] * wb[b][e];
                        pacc[a][b] += xa[a][e] * vb[b][e];
                    }
        }
    }
    __syncthreads();
#pragma unroll
    for (int j = 0; j < 4; ++j) {
        int f = j * 1024 + t * 4;
        int nl = f >> 6, r = f & 63;
        f32x4 uu = *(const f32x4*)&U[(size_t)(n0 + nl) * R_ + r];
        f32x4 ss = *(const f32x4*)&S[r];
        f32x4 us = uu * ss;
        *(f32x4*)&sV[nl][r] = us;
    }
#pragma unroll
    for (int a = 0; a < 4; ++a)
#pragma unroll
        for (int b = 0; b < 4; ++b) sW[tm * 4 + a][tn * 4 + b] = pacc[a][b];
    __syncthreads();
#pragma unroll
    for (int a = 0; a < 4; ++a)
#pragma unroll
        for (int b = 0; b < 4; ++b) {
            float s2 = acc[a][b];
            for (int r = 0; r < R_; ++r) s2 += sW[tm * 4 + a][r] * sV[tn * 4 + b][r];
            out[(size_t)(m0 + tm * 4 + a) * N_ + n0 + tn * 4 + b] = s2 + bias[n0 + tn * 4 + b];
        }
}

extern "C" void kernel_launch(void* const* d_in, const int* in_sizes, int n_in,
                              void* d_out, int out_size, void* d_ws, size_t ws_size,
                              hipStream_t stream) {
    const float* x    = (const float*)d_in[0];
    const float* wm   = (const float*)d_in[1];
    const float* U    = (const float*)d_in[2];
    const float* S    = (const float*)d_in[3];
    const float* V    = (const float*)d_in[4];
    const float* bias = (const float*)d_in[5];
    float* out = (float*)d_out;

    const size_t szA  = (size_t)M_ * K_ * 2;   // 128 MiB per planar x-split buffer
    const size_t szW  = (size_t)N_ * K_ * 2;   //  32 MiB per planar W-split buffer
    const size_t szUS = (size_t)N_ * R_ * 4;   //   1 MiB

    if (ws_size >= 2 * szA + 2 * szW + szUS) {
        ushort_t* hiA = (ushort_t*)d_ws;
        ushort_t* loA = (ushort_t*)((char*)d_ws + szA);
        ushort_t* hiW = (ushort_t*)((char*)d_ws + 2 * szA);
        ushort_t* loW = (ushort_t*)((char*)d_ws + 2 * szA + szW);
        float*    US  = (float*)((char*)d_ws + 2 * szA + 2 * szW);
        k_fold_us<<<dim3((N_ * R_ + 255) / 256), dim3(256), 0, stream>>>(U, S, US);
        k_fuse_w<<<dim3((N_ / 64) * (K_ / 128)), dim3(256), 0, stream>>>(wm, US, V, hiW, loW);
        k_split_x<<<dim3(M_ * K_ / 2048), dim3(256), 0, stream>>>(x, hiA, loA);
        k_gemm_8ph<<<dim3((M_ / BM) * (N_ / BN)), dim3(512), 0, stream>>>(
            hiA, loA, hiW, loW, bias, out);
    } else if (ws_size >= 2 * szW + szUS) {
        ushort_t* hiW = (ushort_t*)d_ws;
        ushort_t* loW = (ushort_t*)((char*)d_ws + szW);
        float*    US  = (float*)((char*)d_ws + 2 * szW);
        k_fold_us<<<dim3((N_ * R_ + 255) / 256), dim3(256), 0, stream>>>(U, S, US);
        k_fuse_w<<<dim3((N_ / 64) * (K_ / 128)), dim3(256), 0, stream>>>(wm, US, V, hiW, loW);
        k_gemm_small<<<dim3((M_ / 128) * (N_ / 128)), dim3(256), 0, stream>>>(
            x, hiW, loW, bias, out);
    } else {
        k_naive<<<dim3((M_ / 64) * (N_ / 64)), dim3(256), 0, stream>>>(x, wm, U, S, V, bias, out);
    }
}

// Round 7
// 1872.066 us; speedup vs baseline: 1.3364x; 1.0005x over previous
//
#include <hip/hip_runtime.h>
#include <hip/hip_bf16.h>
#include <stdint.h>

#define DI __device__ __forceinline__

typedef __attribute__((ext_vector_type(4))) float f32x4;
typedef __attribute__((ext_vector_type(8))) short bf16x8;   // 8 bf16 = 4 VGPR (MFMA A/B frag)
typedef __attribute__((ext_vector_type(4))) short s16x4;

typedef unsigned short ushort_t;

constexpr int M_ = 16384;   // B*T
constexpr int N_ = 4096;    // OUT
constexpr int K_ = 4096;    // IN
constexpr int R_ = 64;

// big-tile GEMM geometry
constexpr int BM = 256, BN = 256, BK = 64;
constexpr int NSEG = 3;
constexpr int NT_SEG = K_ / BK;          // 64 K-tiles per segment
constexpr int TOT_T = NSEG * NT_SEG;     // 192 total K-tiles (even; NIT = 96)

// ---------- bf16 split helpers ----------
DI ushort_t f32_to_bf16_rne(float f) {
    unsigned u = __builtin_bit_cast(unsigned, f);
    u += 0x7FFFu + ((u >> 16) & 1u);           // round-nearest-even
    return (ushort_t)(u >> 16);
}
DI float bf16_to_f32(ushort_t h) {
    return __builtin_bit_cast(float, (unsigned)h << 16);
}

DI void async_cp16(const void* g, void* l) {
    __builtin_amdgcn_global_load_lds(
        (const __attribute__((address_space(1))) unsigned*)g,
        (__attribute__((address_space(3))) unsigned*)l, 16, 0, 0);
}

// barrier with compiler memory fences
#define BAR() do { asm volatile("" ::: "memory"); \
                   __builtin_amdgcn_s_barrier(); \
                   asm volatile("" ::: "memory"); } while (0)
// phase mid-point: barrier, drain prev-phase ds_reads, pin (rule #18), boost prio
#define MID() do { BAR(); \
                   asm volatile("s_waitcnt lgkmcnt(0)" ::: "memory"); \
                   __builtin_amdgcn_sched_barrier(0); \
                   __builtin_amdgcn_s_setprio(1); } while (0)
#define ENDP() do { __builtin_amdgcn_s_setprio(0); BAR(); } while (0)

// ---------- prep 1: W = weight_main + (U*S) @ V  ->  planar hiW, loW (bf16) ----------
// US fold done inline (US[n][r] = U[n][r]*S[r]); block = 64 n-rows x 128 k-cols
__global__ __launch_bounds__(256) void k_fuse_w(const float* __restrict__ WM,
                                                const float* __restrict__ U,
                                                const float* __restrict__ S,
                                                const float* __restrict__ V,
                                                ushort_t* __restrict__ hiW,
                                                ushort_t* __restrict__ loW) {
    __shared__ __align__(16) float sUS[64][68];    // padded rows
    __shared__ __align__(16) float sV[64][128];
    int t = threadIdx.x;
    int n0 = (blockIdx.x >> 5) * 64;
    int k0 = (blockIdx.x & 31) * 128;
#pragma unroll
    for (int j = 0; j < 4; ++j) {                  // US tile 64x64, folded on load
        int f = j * 1024 + t * 4;
        int r = f >> 6, c = f & 63;
        f32x4 uu = *(const f32x4*)&U[(size_t)(n0 + r) * R_ + c];
        f32x4 ss = *(const f32x4*)&S[c];
        *(f32x4*)&sUS[r][c] = uu * ss;
    }
#pragma unroll
    for (int j = 0; j < 8; ++j) {                  // V tile 64x128
        int f = j * 1024 + t * 4;
        int r = f >> 7, c = f & 127;
        *(f32x4*)&sV[r][c] = *(const f32x4*)&V[(size_t)r * K_ + k0 + c];
    }
    __syncthreads();
    int tn = t >> 5;
    int tk = t & 31;
    float acc[8][4] = {};
    for (int r = 0; r < R_; ++r) {
        f32x4 vv = *(const f32x4*)&sV[r][tk * 4];
#pragma unroll
        for (int a = 0; a < 8; ++a) {
            float u = sUS[tn * 8 + a][r];
#pragma unroll
            for (int c = 0; c < 4; ++c) acc[a][c] += u * vv[c];
        }
    }
#pragma unroll
    for (int a = 0; a < 8; ++a) {
        int n = n0 + tn * 8 + a;
        int k = k0 + tk * 4;
        f32x4 wmv = *(const f32x4*)&WM[(size_t)n * K_ + k];
        s16x4 h4, l4;
#pragma unroll
        for (int c = 0; c < 4; ++c) {
            float w = wmv[c] + acc[a][c];
            ushort_t h = f32_to_bf16_rne(w);
            h4[c] = (short)h;
            l4[c] = (short)f32_to_bf16_rne(w - bf16_to_f32(h));
        }
        *(s16x4*)&hiW[(size_t)n * K_ + k] = h4;
        *(s16x4*)&loW[(size_t)n * K_ + k] = l4;
    }
}

// ---------- prep 2: x -> planar hiA, loA (bf16) ----------
__global__ __launch_bounds__(256) void k_split_x(const float* __restrict__ X,
                                                 ushort_t* __restrict__ hiA,
                                                 ushort_t* __restrict__ loA) {
    size_t i = ((size_t)blockIdx.x * 256 + threadIdx.x) * 8;
    f32x4 a = *(const f32x4*)&X[i];
    f32x4 b = *(const f32x4*)&X[i + 4];
    bf16x8 h, l;
#pragma unroll
    for (int j = 0; j < 4; ++j) {
        ushort_t ha = f32_to_bf16_rne(a[j]);
        ushort_t hb = f32_to_bf16_rne(b[j]);
        h[j]     = (short)ha;
        h[4 + j] = (short)hb;
        l[j]     = (short)f32_to_bf16_rne(a[j] - bf16_to_f32(ha));
        l[4 + j] = (short)f32_to_bf16_rne(b[j] - bf16_to_f32(hb));
    }
    *(bf16x8*)&hiA[i] = h;
    *(bf16x8*)&loA[i] = l;
}

// ---------- main GEMM: 256x256, BK=64, 8 waves, 8-phase + register-prefetch ----------
// out = hiA@hiW^T + loA@hiW^T + hiA@loW^T + bias  (3 planar bf16 segments)
//
// Phase decomposition: (i-half x ks). Each phase's 16 MFMAs consume frags loaded
// in the PREVIOUS phase; each phase issues the NEXT phase's 4 or 8 ds_read_b128
// inside its MFMA window (after lgkmcnt(0)+sched_barrier, inside setprio region).
// Frag rotation (all names static -> registers, rule #20):
//   ph1: MFMA(i0-3,ks0: aX,bX)  reads-> aY=A[i4-7,ks0]
//   ph2: MFMA(i4-7,ks0: aY,bX)  reads-> aX=A[i0-3,ks1], bY=B[ks1]
//   ph3: MFMA(i0-3,ks1: aX,bY)  reads-> aY=A[i4-7,ks1]
//   ph4: MFMA(i4-7,ks1: aY,bY)  reads-> aX,bX from NEXT tile's buffer
//   (ph5-8 mirror on the other LDS buffer)
// Stage schedule + vmcnt checkpoints (audited r5/r6):
//   ph1:A(to,0) ph2:A(to,1) ph3:B(ne,0) ph4:B(ne,1)+vmcnt(4)
//   ph5:A(ne,0) ph6:A(ne,1) ph7:B(no,0) ph8:B(no,1)+vmcnt(4)
// At ph4's vmcnt(4): steady-state outstanding = B(to)[4 prev ph7/8] + A(to)[4]
// + B(ne)[4] = 12 -> drains B(to)+A(to) BEFORE the barrier; every wave verifies
// its own loads pre-barrier, so post-barrier buf1 is fully landed for all waves.
// Symmetric at ph8 for tile ne. No vmcnt(0) in the loop. WAR: every stage issue
// is >=1 barrier after the last read of its half-region (checked per phase).
// Wrap-tile stages in the last iteration hit dead regions only.
__global__ __launch_bounds__(512, 2) void k_gemm_8ph(const ushort_t* __restrict__ hiA,
                                                     const ushort_t* __restrict__ loA,
                                                     const ushort_t* __restrict__ hiW,
                                                     const ushort_t* __restrict__ loW,
                                                     const float* __restrict__ bias,
                                                     float* __restrict__ out) {
    __shared__ __align__(16) ushort_t lA[2][BM * BK];   // 2 x 32 KiB
    __shared__ __align__(16) ushort_t lB[2][BN * BK];   // 2 x 32 KiB  (128 KiB total)

    // XCD-bijective swizzle; grid = 1024 (divisible by 8)
    int bid = blockIdx.x;
    int wg  = (bid & 7) * (gridDim.x >> 3) + (bid >> 3);
    int m0  = (wg >> 4) * BM;
    int n0  = (wg & 15) * BN;

    int tid  = threadIdx.x;
    int lane = tid & 63;
    int w    = tid >> 6;
    int wr   = w >> 2;            // 0..1  (128 M-rows each)
    int wc   = w & 3;             // 0..3  (64 N-cols each)
    int fr   = lane & 15;
    int fq   = lane >> 4;

    f32x4 acc[8][4] = {};

    // stage one half-tile; chunk-XOR swizzle on the GLOBAL source (linear LDS dest)
    auto stageA = [&](int tau, int h) {
        int seg = tau >> 6;
        const ushort_t* As = (seg == 1) ? loA : hiA;
        int k0 = (tau & (NT_SEG - 1)) * BK;
        ushort_t* dst = &lA[tau & 1][h * (128 * 64)];
#pragma unroll
        for (int j = 0; j < 2; ++j) {
            int ci  = j * 512 + tid;          // 16B chunk id: row=ci>>3, chunk=ci&7
            int row = ci >> 3, pc = ci & 7;
            int lc  = pc ^ (row & 7);         // involution
            async_cp16(&As[(size_t)(m0 + h * 128 + row) * K_ + k0 + lc * 8], &dst[ci * 8]);
        }
    };
    auto stageB = [&](int tau, int h) {
        int seg = tau >> 6;
        const ushort_t* Bs = (seg == 2) ? loW : hiW;
        int k0 = (tau & (NT_SEG - 1)) * BK;
        ushort_t* dst = &lB[tau & 1][h * (128 * 64)];
#pragma unroll
        for (int j = 0; j < 2; ++j) {
            int ci  = j * 512 + tid;
            int row = ci >> 3, pc = ci & 7;
            int lc  = pc ^ (row & 7);
            async_cp16(&Bs[(size_t)(n0 + h * 128 + row) * K_ + k0 + lc * 8], &dst[ci * 8]);
        }
    };
    auto rdA = [&](const ushort_t* la, int i, int ks) -> bf16x8 {
        int row = wr * 128 + i * 16 + fr;
        return *(const bf16x8*)&la[row * 64 + (((ks * 4 + fq) ^ (row & 7)) << 3)];
    };
    auto rdB = [&](const ushort_t* lb, int j, int ks) -> bf16x8 {
        int row = wc * 64 + j * 16 + fr;
        return *(const bf16x8*)&lb[row * 64 + (((ks * 4 + fq) ^ (row & 7)) << 3)];
    };

    bf16x8 aX[4], aY[4], bX[4], bY[4];

#define RD_A(dst, la, ib, ks) do { \
    dst[0] = rdA(la, (ib) + 0, ks); dst[1] = rdA(la, (ib) + 1, ks); \
    dst[2] = rdA(la, (ib) + 2, ks); dst[3] = rdA(la, (ib) + 3, ks); } while (0)
#define RD_B(dst, lb, ks) do { \
    dst[0] = rdB(lb, 0, ks); dst[1] = rdB(lb, 1, ks); \
    dst[2] = rdB(lb, 2, ks); dst[3] = rdB(lb, 3, ks); } while (0)
#define MFMA16(IB, A_, B_) do { \
    _Pragma("unroll") \
    for (int i_ = 0; i_ < 4; ++i_) \
        _Pragma("unroll") \
        for (int j_ = 0; j_ < 4; ++j_) \
            acc[(IB) + i_][j_] = __builtin_amdgcn_mfma_f32_16x16x32_bf16( \
                A_[i_], B_[j_], acc[(IB) + i_][j_], 0, 0, 0); } while (0)

    const ushort_t* la0 = lA[0]; const ushort_t* lb0 = lB[0];
    const ushort_t* la1 = lA[1]; const ushort_t* lb1 = lB[1];

    // ---- prologue: tile0 (full) -> buf0; tile1 B-halves -> buf1; 12 loads
    stageB(0, 0); stageB(0, 1); stageA(0, 0); stageA(0, 1);
    stageB(1, 0); stageB(1, 1);
    asm volatile("s_waitcnt vmcnt(4)" ::: "memory");   // oldest 8 = tile0 landed
    BAR();
    RD_A(aX, la0, 0, 0); RD_B(bX, lb0, 0);             // pre-issue ph1's frags

    constexpr int NIT = TOT_T / 2;   // 96
    for (int it = 0; it < NIT; ++it) {
        int to = 2 * it + 1;                 // odd tile (buf1), computed ph5-8
        int ne = (2 * it + 2) % TOT_T;       // next even tile -> buf0
        int no = (2 * it + 3) % TOT_T;       // next odd tile  -> buf1

        // ---- ph1
        stageA(to, 0);
        MID();
        RD_A(aY, la0, 4, 0);
        MFMA16(0, aX, bX);
        ENDP();
        // ---- ph2
        stageA(to, 1);
        MID();
        RD_A(aX, la0, 0, 1); RD_B(bY, lb0, 1);
        MFMA16(4, aY, bX);
        ENDP();
        // ---- ph3
        stageB(ne, 0);
        MID();
        RD_A(aY, la0, 4, 1);
        MFMA16(0, aX, bY);
        ENDP();
        // ---- ph4: vmcnt checkpoint for tile `to` BEFORE its first reads
        stageB(ne, 1);
        asm volatile("s_waitcnt vmcnt(4)" ::: "memory");
        MID();
        RD_A(aX, la1, 0, 0); RD_B(bX, lb1, 0);
        MFMA16(4, aY, bY);
        ENDP();
        // ---- ph5
        stageA(ne, 0);
        MID();
        RD_A(aY, la1, 4, 0);
        MFMA16(0, aX, bX);
        ENDP();
        // ---- ph6
        stageA(ne, 1);
        MID();
        RD_A(aX, la1, 0, 1); RD_B(bY, lb1, 1);
        MFMA16(4, aY, bX);
        ENDP();
        // ---- ph7
        stageB(no, 0);
        MID();
        RD_A(aY, la1, 4, 1);
        MFMA16(0, aX, bY);
        ENDP();
        // ---- ph8: vmcnt checkpoint for tile `ne` BEFORE its first reads
        stageB(no, 1);
        asm volatile("s_waitcnt vmcnt(4)" ::: "memory");
        MID();
        RD_A(aX, la0, 0, 0); RD_B(bX, lb0, 0);
        MFMA16(4, aY, bY);
        ENDP();
    }

    asm volatile("s_waitcnt vmcnt(0)" ::: "memory");   // drain wrap stages

#undef RD_A
#undef RD_B
#undef MFMA16

    // epilogue: C/D layout col=lane&15, row=(lane>>4)*4+reg  [m89]
    float bcol[4];
#pragma unroll
    for (int j = 0; j < 4; ++j) bcol[j] = bias[n0 + wc * 64 + j * 16 + fr];
#pragma unroll
    for (int i = 0; i < 8; ++i) {
        int gm = m0 + wr * 128 + i * 16 + fq * 4;
#pragma unroll
        for (int j = 0; j < 4; ++j) {
            int gn = n0 + wc * 64 + j * 16 + fr;
#pragma unroll
            for (int r2 = 0; r2 < 4; ++r2)
                out[(size_t)(gm + r2) * N_ + gn] = acc[i][j][r2] + bcol[j];
        }
    }
}

// ---------- tier-2 GEMM (ws fits only W): 128x128 m97 structure, in-register x split ----------
__global__ __launch_bounds__(256, 2) void k_gemm_small(const float* __restrict__ X,
                                                       const ushort_t* __restrict__ hiW,
                                                       const ushort_t* __restrict__ loW,
                                                       const float* __restrict__ bias,
                                                       float* __restrict__ out) {
    __shared__ __align__(16) ushort_t lA[128 * 64];
    __shared__ __align__(16) ushort_t lB[128 * 64];
    int bid = blockIdx.x;
    int cpx = gridDim.x >> 3;
    int wg  = (bid & 7) * cpx + (bid >> 3);
    constexpr int NBN = N_ / 128;
    int m0 = (wg / NBN) * 128;
    int n0 = (wg % NBN) * 128;
    int tid  = threadIdx.x;
    int lane = tid & 63;
    int w    = tid >> 6;
    int wr   = w >> 1, wc = w & 1;
    int fr   = lane & 15;
    int fq   = lane >> 4;
    f32x4 acc[4][4] = {};
    for (int seg = 0; seg < 3; ++seg) {
        const ushort_t* Bs = (seg == 2) ? loW : hiW;
        bool wantLo = (seg == 1);
        for (int kt = 0; kt < K_ / 64; ++kt) {
            int k0 = kt * 64;
#pragma unroll
            for (int j = 0; j < 4; ++j) {
                int f = j * 2048 + tid * 8;
                int row = f >> 6, col = f & 63;
                async_cp16(&Bs[(size_t)(n0 + row) * K_ + k0 + col], &lB[f]);
            }
#pragma unroll
            for (int j = 0; j < 4; ++j) {
                int f = j * 2048 + tid * 8;
                int row = f >> 6, c = f & 63;
                const float* xp = &X[(size_t)(m0 + row) * K_ + k0 + c];
                f32x4 x0 = *(const f32x4*)xp;
                f32x4 x1 = *(const f32x4*)(xp + 4);
                bf16x8 o;
#pragma unroll
                for (int e = 0; e < 4; ++e) {
                    ushort_t h0 = f32_to_bf16_rne(x0[e]);
                    ushort_t h1 = f32_to_bf16_rne(x1[e]);
                    o[e]     = (short)(wantLo ? f32_to_bf16_rne(x0[e] - bf16_to_f32(h0)) : h0);
                    o[4 + e] = (short)(wantLo ? f32_to_bf16_rne(x1[e] - bf16_to_f32(h1)) : h1);
                }
                *(bf16x8*)&lA[f] = o;
            }
            __syncthreads();
#pragma unroll
            for (int ks = 0; ks < 2; ++ks) {
                bf16x8 af[4], bfv[4];
#pragma unroll
                for (int i = 0; i < 4; ++i) {
                    af[i]  = *(const bf16x8*)&lA[(wr * 64 + i * 16 + fr) * 64 + ks * 32 + fq * 8];
                    bfv[i] = *(const bf16x8*)&lB[(wc * 64 + i * 16 + fr) * 64 + ks * 32 + fq * 8];
                }
#pragma unroll
                for (int i = 0; i < 4; ++i)
#pragma unroll
                    for (int j = 0; j < 4; ++j)
                        acc[i][j] = __builtin_amdgcn_mfma_f32_16x16x32_bf16(af[i], bfv[j], acc[i][j], 0, 0, 0);
            }
            __syncthreads();
        }
    }
    float bcol[4];
#pragma unroll
    for (int j = 0; j < 4; ++j) bcol[j] = bias[n0 + wc * 64 + j * 16 + fr];
#pragma unroll
    for (int i = 0; i < 4; ++i) {
        int gm = m0 + wr * 64 + i * 16 + fq * 4;
#pragma unroll
        for (int j = 0; j < 4; ++j) {
            int gn = n0 + wc * 64 + j * 16 + fr;
#pragma unroll
            for (int r2 = 0; r2 < 4; ++r2)
                out[(size_t)(gm + r2) * N_ + gn] = acc[i][j][r2] + bcol[j];
        }
    }
}

// ---------- ws-free correct fallback (fp32 vector; insurance only) ----------
__global__ __launch_bounds__(256) void k_naive(const float* __restrict__ X,
                                               const float* __restrict__ WM,
                                               const float* __restrict__ U,
                                               const float* __restrict__ S,
                                               const float* __restrict__ V,
                                               const float* __restrict__ bias,
                                               float* __restrict__ out) {
    __shared__ __align__(16) float sX[64][68];
    __shared__ __align__(16) float sW[64][68];
    __shared__ __align__(16) float sV[64][68];
    int t = threadIdx.x;
    int m0 = (blockIdx.x >> 6) * 64;
    int n0 = (blockIdx.x & 63) * 64;
    int tm = t >> 4, tn = t & 15;
    float acc[4][4] = {}, pacc[4][4] = {};
    for (int kc = 0; kc < K_ / 64; ++kc) {
        __syncthreads();
#pragma unroll
        for (int j = 0; j < 4; ++j) {
            int f = j * 1024 + t * 4;
            int r = f >> 6, c = f & 63;
            *(f32x4*)&sX[r][c] = *(const f32x4*)&X[(size_t)(m0 + r) * K_ + kc * 64 + c];
            *(f32x4*)&sW[r][c] = *(const f32x4*)&WM[(size_t)(n0 + r) * K_ + kc * 64 + c];
            *(f32x4*)&sV[r][c] = *(const f32x4*)&V[(size_t)r * K_ + kc * 64 + c];
        }
        __syncthreads();
        for (int k4 = 0; k4 < 16; ++k4) {
            f32x4 xa[4], wb[4], vb[4];
#pragma unroll
            for (int a = 0; a < 4; ++a) xa[a] = *(const f32x4*)&sX[tm * 4 + a][k4 * 4];
#pragma unroll
            for (int b = 0; b < 4; ++b) {
                wb[b] = *(const f32x4*)&sW[tn * 4 + b][k4 * 4];
                vb[b] = *(const f32x4*)&sV[tn * 4 + b][k4 * 4];
            }
#pragma unroll
            for (int a = 0; a < 4; ++a)
#pragma unroll
                for (int b = 0; b < 4; ++b)
#pragma unroll
                    for (int e = 0; e < 4; ++e) {
                        acc[a][b]  += xa[a][e] * wb[b][e];
                        pacc[a][b] += xa[a][e] * vb[b][e];
                    }
        }
    }
    __syncthreads();
#pragma unroll
    for (int j = 0; j < 4; ++j) {
        int f = j * 1024 + t * 4;
        int nl = f >> 6, r = f & 63;
        f32x4 uu = *(const f32x4*)&U[(size_t)(n0 + nl) * R_ + r];
        f32x4 ss = *(const f32x4*)&S[r];
        f32x4 us = uu * ss;
        *(f32x4*)&sV[nl][r] = us;
    }
#pragma unroll
    for (int a = 0; a < 4; ++a)
#pragma unroll
        for (int b = 0; b < 4; ++b) sW[tm * 4 + a][tn * 4 + b] = pacc[a][b];
    __syncthreads();
#pragma unroll
    for (int a = 0; a < 4; ++a)
#pragma unroll
        for (int b = 0; b < 4; ++b) {
            float s2 = acc[a][b];
            for (int r = 0; r < R_; ++r) s2 += sW[tm * 4 + a][r] * sV[tn * 4 + b][r];
            out[(size_t)(m0 + tm * 4 + a) * N_ + n0 + tn * 4 + b] = s2 + bias[n0 + tn * 4 + b];
        }
}

extern "C" void kernel_launch(void* const* d_in, const int* in_sizes, int n_in,
                              void* d_out, int out_size, void* d_ws, size_t ws_size,
                              hipStream_t stream) {
    const float* x    = (const float*)d_in[0];
    const float* wm   = (const float*)d_in[1];
    const float* U    = (const float*)d_in[2];
    const float* S    = (const float*)d_in[3];
    const float* V    = (const float*)d_in[4];
    const float* bias = (const float*)d_in[5];
    float* out = (float*)d_out;

    const size_t szA = (size_t)M_ * K_ * 2;   // 128 MiB per planar x-split buffer
    const size_t szW = (size_t)N_ * K_ * 2;   //  32 MiB per planar W-split buffer

    if (ws_size >= 2 * szA + 2 * szW) {
        ushort_t* hiA = (ushort_t*)d_ws;
        ushort_t* loA = (ushort_t*)((char*)d_ws + szA);
        ushort_t* hiW = (ushort_t*)((char*)d_ws + 2 * szA);
        ushort_t* loW = (ushort_t*)((char*)d_ws + 2 * szA + szW);
        k_fuse_w<<<dim3((N_ / 64) * (K_ / 128)), dim3(256), 0, stream>>>(wm, U, S, V, hiW, loW);
        k_split_x<<<dim3(M_ * K_ / 2048), dim3(256), 0, stream>>>(x, hiA, loA);
        k_gemm_8ph<<<dim3((M_ / BM) * (N_ / BN)), dim3(512), 0, stream>>>(
            hiA, loA, hiW, loW, bias, out);
    } else if (ws_size >= 2 * szW) {
        ushort_t* hiW = (ushort_t*)d_ws;
        ushort_t* loW = (ushort_t*)((char*)d_ws + szW);
        k_fuse_w<<<dim3((N_ / 64) * (K_ / 128)), dim3(256), 0, stream>>>(wm, U, S, V, hiW, loW);
        k_gemm_small<<<dim3((M_ / 128) * (N_ / 128)), dim3(256), 0, stream>>>(
            x, hiW, loW, bias, out);
    } else {
        k_naive<<<dim3((M_ / 64) * (N_ / 64)), dim3(256), 0, stream>>>(x, wm, U, S, V, bias, out);
    }
}